// Round 1
// baseline (808.694 us; speedup 1.0000x reference)
//
#include <hip/hip_runtime.h>

#define Hdim 1024
#define Bdim 32
#define Sdim 2048

typedef __attribute__((ext_vector_type(8))) __bf16 bf16x8;
typedef __attribute__((ext_vector_type(4))) float f32x4;

#define GLOAD_LDS16(gp, lp)                                                              \
  __builtin_amdgcn_global_load_lds(                                                     \
      (const __attribute__((address_space(1))) unsigned int*)(gp),                      \
      (__attribute__((address_space(3))) unsigned int*)(lp), 16, 0, 0)

// ---------------------------------------------------------------------------
// Ua (H x H fp32, row-major k-major) -> bf16 in [ntile][k8][n][8] order so the
// GEMM's B staging is fully contiguous per K-chunk (8 KiB per chunk per ntile).
__global__ __launch_bounds__(256) void convert_ua_kernel(const float* __restrict__ Ua,
                                                         __bf16* __restrict__ ubt) {
  int du = blockIdx.x * 256 + threadIdx.x;  // 0..131071 (16B units)
  int n  = du & 127;
  int k8 = (du >> 7) & 127;
  int nt = du >> 14;
  int ng = nt * 128 + n;
  bf16x8 t;
#pragma unroll
  for (int j = 0; j < 8; ++j)
    t[j] = (__bf16)Ua[(k8 * 8 + j) * Hdim + ng];
  *(bf16x8*)(ubt + (size_t)du * 8) = t;
}

// ---------------------------------------------------------------------------
// qc[b,h] = query[b] @ Wa_w + Wa_b + Ua_b   (fp32, tiny: 67 MFLOP)
__global__ __launch_bounds__(256) void qc_kernel(const float* __restrict__ q,
                                                 const float* __restrict__ Wa,
                                                 const float* __restrict__ Wab,
                                                 const float* __restrict__ Uab,
                                                 float* __restrict__ qc) {
  int b = blockIdx.y;
  int h = blockIdx.x * 256 + threadIdx.x;
  float acc = Wab[h] + Uab[h];
  const float* qr = q + b * Hdim;
#pragma unroll 16
  for (int i = 0; i < Hdim; ++i)
    acc = fmaf(qr[i], Wa[i * Hdim + h], acc);  // Wa column read is coalesced across h
  qc[b * Hdim + h] = acc;
}

// ---------------------------------------------------------------------------
// Fused score GEMM: for row r = s*32+b of key, partial[r, nt] =
//   sum_{n in ntile} va[n] * tanh(qc[b,n] + sum_k key[r,k]*Ua[k,n])
// 128x128 tile, BK=32, bf16 MFMA 16x16x32, A staged as fp32 via global_load_lds
// (layout [k4][row] -> conflict-free b128 LDS reads), cvt to bf16 at frag load.
__global__ __launch_bounds__(256) void gemm_scores_kernel(const float* __restrict__ key,
                                                          const __bf16* __restrict__ ubt,
                                                          const float* __restrict__ qc,
                                                          const float* __restrict__ va,
                                                          float* __restrict__ part) {
  __shared__ __align__(16) float AsQ[4096];  // K-loop: A tile [k4][row]; epilogue: qc tile [b][n]
  __shared__ __align__(16) __bf16 Bs[4096];  // B tile [k8][n] (bf16x8 units)
  __shared__ float red[256];

  const int tid  = threadIdx.x;
  const int w    = tid >> 6;
  const int lane = tid & 63;
  const int quad = lane >> 4;
  const int l16  = lane & 15;
  const int nt = blockIdx.x;  // 0..7  fast dim: the 8 blocks sharing A rows are adjacent
  const int mt = blockIdx.y;  // 0..511
  const int r0 = mt * 128;
  const int n0 = nt * 128;
  const int wm = (w & 1) * 64;
  const int wn = (w >> 1) * 64;

  f32x4 acc[4][4] = {};

  for (int kc = 0; kc < Hdim; kc += 32) {
    // stage A: 128 rows x 32 k fp32 (16 KiB), dest is lane-linear (base + lane*16)
#pragma unroll
    for (int it = 0; it < 4; ++it) {
      int u  = it * 256 + tid;  // float4-unit index: u = k4*128 + row
      int k4 = u >> 7, row = u & 127;
      GLOAD_LDS16(key + (size_t)(r0 + row) * Hdim + kc + k4 * 4, AsQ + u * 4);
    }
    // stage B: 128 n x 32 k bf16 (8 KiB), source contiguous thanks to ubt layout
#pragma unroll
    for (int it = 0; it < 2; ++it) {
      int u = it * 256 + tid;  // bf16x8-unit index: u = k8l*128 + n
      GLOAD_LDS16(ubt + ((size_t)nt * 16384 + (kc >> 3) * 128 + u) * 8, Bs + u * 8);
    }
    __syncthreads();

    bf16x8 bfr[4];
#pragma unroll
    for (int j = 0; j < 4; ++j)
      bfr[j] = *(const bf16x8*)&Bs[(quad * 128 + wn + j * 16 + l16) * 8];

    bf16x8 afr[4];
#pragma unroll
    for (int i = 0; i < 4; ++i) {
      int ml = wm + i * 16 + l16;
      float4 f0 = *(const float4*)&AsQ[((quad * 2) * 128 + ml) * 4];      // k = q*8..+3
      float4 f1 = *(const float4*)&AsQ[((quad * 2 + 1) * 128 + ml) * 4];  // k = q*8+4..+7
      bf16x8 a;
      a[0] = (__bf16)f0.x; a[1] = (__bf16)f0.y; a[2] = (__bf16)f0.z; a[3] = (__bf16)f0.w;
      a[4] = (__bf16)f1.x; a[5] = (__bf16)f1.y; a[6] = (__bf16)f1.z; a[7] = (__bf16)f1.w;
      afr[i] = a;
    }

#pragma unroll
    for (int i = 0; i < 4; ++i)
#pragma unroll
      for (int j = 0; j < 4; ++j)
        acc[i][j] = __builtin_amdgcn_mfma_f32_16x16x32_bf16(afr[i], bfr[j], acc[i][j], 0, 0, 0);

    __syncthreads();
  }

  // stage qc tile (32 b-rows x 128 n-cols) into AsQ (reuse; barrier above protects)
#pragma unroll
  for (int it = 0; it < 16; ++it) {
    int u = it * 256 + tid;
    AsQ[u] = qc[(u >> 7) * Hdim + n0 + (u & 127)];
  }
  __syncthreads();

  float vav[4];
#pragma unroll
  for (int j = 0; j < 4; ++j) vav[j] = va[n0 + wn + j * 16 + l16];

  // C/D layout (m89-verified): col = lane&15 (n), row = quad*4 + reg (m)
#pragma unroll
  for (int i = 0; i < 4; ++i) {
#pragma unroll
    for (int rg = 0; rg < 4; ++rg) {
      int b = (i & 1) * 16 + quad * 4 + rg;  // = (global row) & 31
      float sum = 0.f;
#pragma unroll
      for (int j = 0; j < 4; ++j) {
        float v = acc[i][j][rg] + AsQ[b * 128 + wn + j * 16 + l16];
        v = fminf(fmaxf(v, -15.f), 15.f);
        float e = __expf(2.f * v);                                   // tanh = (e-1)/(e+1)
        sum += (e - 1.f) * __builtin_amdgcn_rcpf(e + 1.f) * vav[j];
      }
      // reduce over the 16 lanes sharing this output row (n-direction)
#pragma unroll
      for (int off = 1; off < 16; off <<= 1)
        sum += __shfl_xor(sum, off, 64);
      if (l16 == 0)
        red[(wm + i * 16 + quad * 4 + rg) * 2 + (w >> 1)] = sum;
    }
  }
  __syncthreads();
  if (tid < 128)
    part[(size_t)(r0 + tid) * 8 + nt] = red[tid * 2] + red[tid * 2 + 1];
}

// ---------------------------------------------------------------------------
// softmax over S per batch; va_b omitted (constant shift cancels in softmax)
__global__ __launch_bounds__(256) void softmax_kernel(const float* __restrict__ part,
                                                      float* __restrict__ dout) {
  int b = blockIdx.x, t = threadIdx.x;
  int w = t >> 6, lane = t & 63;
  __shared__ float red1[4], red2[4];
  float sc[8];
  float m = -1e30f;
#pragma unroll
  for (int c = 0; c < 8; ++c) {
    int s = c * 256 + t;
    const float4* p = (const float4*)&part[(size_t)(s * 32 + b) * 8];
    float4 p0 = p[0], p1 = p[1];
    float v = ((p0.x + p0.y) + (p0.z + p0.w)) + ((p1.x + p1.y) + (p1.z + p1.w));
    sc[c] = v;
    m = fmaxf(m, v);
  }
#pragma unroll
  for (int off = 1; off < 64; off <<= 1) m = fmaxf(m, __shfl_xor(m, off, 64));
  if (lane == 0) red1[w] = m;
  __syncthreads();
  m = fmaxf(fmaxf(red1[0], red1[1]), fmaxf(red1[2], red1[3]));
  float sum = 0.f;
#pragma unroll
  for (int c = 0; c < 8; ++c) { sc[c] = __expf(sc[c] - m); sum += sc[c]; }
#pragma unroll
  for (int off = 1; off < 64; off <<= 1) sum += __shfl_xor(sum, off, 64);
  if (lane == 0) red2[w] = sum;
  __syncthreads();
  float inv = 1.f / (red2[0] + red2[1] + red2[2] + red2[3]);
#pragma unroll
  for (int c = 0; c < 8; ++c)
    dout[32768 + b * 2048 + c * 256 + t] = sc[c] * inv;
}

// ---------------------------------------------------------------------------
// context partials: cpart[sc][b][h] = sum_{s in chunk} w[b,s]*key[s,b,h]
__global__ __launch_bounds__(256) void ctx_part_kernel(const float* __restrict__ key,
                                                       const float* __restrict__ dout,
                                                       float* __restrict__ cpart) {
  int sc = blockIdx.x;  // 0..31
  int b  = blockIdx.y;  // 0..31
  int t  = threadIdx.x;
  float4 acc = make_float4(0.f, 0.f, 0.f, 0.f);
  int s0 = sc * 64;
#pragma unroll 8
  for (int s = s0; s < s0 + 64; ++s) {
    float wgt = dout[32768 + b * 2048 + s];
    float4 k4 = *(const float4*)&key[((size_t)(s * 32 + b) << 10) + t * 4];
    acc.x = fmaf(wgt, k4.x, acc.x);
    acc.y = fmaf(wgt, k4.y, acc.y);
    acc.z = fmaf(wgt, k4.z, acc.z);
    acc.w = fmaf(wgt, k4.w, acc.w);
  }
  *(float4*)&cpart[((size_t)(sc * 32 + b) << 10) + t * 4] = acc;
}

__global__ __launch_bounds__(256) void ctx_reduce_kernel(const float* __restrict__ cpart,
                                                         float* __restrict__ dout) {
  int o = blockIdx.x * 256 + threadIdx.x;  // 0..32767
  int b = o >> 10, h = o & 1023;
  float s = 0.f;
#pragma unroll
  for (int sc = 0; sc < 32; ++sc)
    s += cpart[((size_t)(sc * 32 + b) << 10) + h];
  dout[o] = s;
}

// ---------------------------------------------------------------------------
extern "C" void kernel_launch(void* const* d_in, const int* in_sizes, int n_in,
                              void* d_out, int out_size, void* d_ws, size_t ws_size,
                              hipStream_t stream) {
  const float* q   = (const float*)d_in[0];  // (32,1,1024)
  const float* key = (const float*)d_in[1];  // (2048,32,1024)
  const float* Waw = (const float*)d_in[2];  // (1024,1024)
  const float* Wab = (const float*)d_in[3];  // (1024,)
  const float* Uaw = (const float*)d_in[4];  // (1024,1024)
  const float* Uab = (const float*)d_in[5];  // (1024,)
  const float* vaw = (const float*)d_in[6];  // (1024,)
  // d_in[7] = va_b: constant shift, cancels in softmax -> unused
  float* out = (float*)d_out;  // [0,32768): context ; [32768,98304): weights

  char* ws = (char*)d_ws;
  float*  qc    = (float*)(ws);                                      // 128 KiB
  __bf16* ubt   = (__bf16*)(ws + (131072));                          // 2 MiB
  float*  part  = (float*)(ws + (131072 + 2097152));                 // 2 MiB
  float*  cpart = (float*)(ws + (131072 + 2097152 + 2097152));       // 4 MiB

  convert_ua_kernel<<<512, 256, 0, stream>>>(Uaw, ubt);
  qc_kernel<<<dim3(4, 32), 256, 0, stream>>>(q, Waw, Wab, Uab, qc);
  gemm_scores_kernel<<<dim3(8, 512), 256, 0, stream>>>(key, ubt, qc, vaw, part);
  softmax_kernel<<<32, 256, 0, stream>>>(part, out);
  ctx_part_kernel<<<dim3(32, 32), 256, 0, stream>>>(key, out, cpart);
  ctx_reduce_kernel<<<128, 256, 0, stream>>>(cpart, out);
}

// Round 2
// 716.035 us; speedup vs baseline: 1.1294x; 1.1294x over previous
//
#include <hip/hip_runtime.h>

#define Hdim 1024
#define Bdim 32
#define Sdim 2048

typedef __attribute__((ext_vector_type(8))) __bf16 bf16x8;
typedef __attribute__((ext_vector_type(4))) float f32x4;

#define GLOAD_LDS16(gp, lp)                                                              \
  __builtin_amdgcn_global_load_lds(                                                     \
      (const __attribute__((address_space(1))) unsigned int*)(gp),                      \
      (__attribute__((address_space(3))) unsigned int*)(lp), 16, 0, 0)

// ---------------------------------------------------------------------------
// key (S*B x H fp32, row-major) -> bf16, same layout. Pure streaming pass.
__global__ __launch_bounds__(256) void convert_key_kernel(const float* __restrict__ key,
                                                          __bf16* __restrict__ bkey) {
  size_t idx = (size_t)blockIdx.x * 256 + threadIdx.x;  // 8 elements per thread
  const float4* src = (const float4*)(key + idx * 8);
  float4 f0 = src[0], f1 = src[1];
  bf16x8 t;
  t[0] = (__bf16)f0.x; t[1] = (__bf16)f0.y; t[2] = (__bf16)f0.z; t[3] = (__bf16)f0.w;
  t[4] = (__bf16)f1.x; t[5] = (__bf16)f1.y; t[6] = (__bf16)f1.z; t[7] = (__bf16)f1.w;
  *(bf16x8*)(bkey + idx * 8) = t;
}

// ---------------------------------------------------------------------------
// Ua (H x H fp32, row-major k-major) -> bf16 in [ntile][k8][n][8] order so the
// GEMM's B staging is fully contiguous per K-chunk (8 KiB per chunk per ntile).
__global__ __launch_bounds__(256) void convert_ua_kernel(const float* __restrict__ Ua,
                                                         __bf16* __restrict__ ubt) {
  int du = blockIdx.x * 256 + threadIdx.x;  // 0..131071 (16B units)
  int n  = du & 127;
  int k8 = (du >> 7) & 127;
  int nt = du >> 14;
  int ng = nt * 128 + n;
  bf16x8 t;
#pragma unroll
  for (int j = 0; j < 8; ++j)
    t[j] = (__bf16)Ua[(k8 * 8 + j) * Hdim + ng];
  *(bf16x8*)(ubt + (size_t)du * 8) = t;
}

// ---------------------------------------------------------------------------
// qc[b,h] = query[b] @ Wa_w + Wa_b + Ua_b   (fp32, tiny: 67 MFLOP)
__global__ __launch_bounds__(256) void qc_kernel(const float* __restrict__ q,
                                                 const float* __restrict__ Wa,
                                                 const float* __restrict__ Wab,
                                                 const float* __restrict__ Uab,
                                                 float* __restrict__ qc) {
  int b = blockIdx.y;
  int h = blockIdx.x * 256 + threadIdx.x;
  float acc = Wab[h] + Uab[h];
  const float* qr = q + b * Hdim;
#pragma unroll 16
  for (int i = 0; i < Hdim; ++i)
    acc = fmaf(qr[i], Wa[i * Hdim + h], acc);
  qc[b * Hdim + h] = acc;
}

// ---------------------------------------------------------------------------
// Fused score GEMM, bf16 A path (m97 structure): 128x128 tile, BK=32,
// A tile [k8][row] bf16 8 KiB + B tile [k8][n] bf16 8 KiB per iter.
// XCD swizzle: all 8 nt-blocks of one mt land on the same XCD (l%8 const).
__global__ __launch_bounds__(256) void gemm_scores_bf16_kernel(const __bf16* __restrict__ bkey,
                                                               const __bf16* __restrict__ ubt,
                                                               const float* __restrict__ qc,
                                                               const float* __restrict__ va,
                                                               float* __restrict__ part) {
  __shared__ __align__(16) __bf16 ABs[8192];  // [0..4095]=A tile, [4096..8191]=B tile; epilogue: qc floats
  __shared__ float red[256];

  const int tid  = threadIdx.x;
  const int w    = tid >> 6;
  const int lane = tid & 63;
  const int quad = lane >> 4;
  const int l16  = lane & 15;

  const int l   = blockIdx.x;
  const int xcd = l & 7;
  const int i2  = l >> 3;
  const int mt  = xcd * 64 + (i2 >> 3);  // 0..511  (same XCD for all 8 nt of one mt)
  const int nt  = i2 & 7;                // 0..7

  const int r0 = mt * 128;
  const int n0 = nt * 128;
  const int wm = (w & 1) * 64;
  const int wn = (w >> 1) * 64;

  __bf16* As = ABs;
  __bf16* Bs = ABs + 4096;

  f32x4 acc[4][4] = {};

  for (int kc = 0; kc < Hdim; kc += 32) {
    // stage A: 128 rows x 32 k bf16 (8 KiB), layout [k8][row][8]
#pragma unroll
    for (int it = 0; it < 2; ++it) {
      int u  = it * 256 + tid;  // bf16x8-unit: u = k8*128 + row
      int k8 = u >> 7, row = u & 127;
      GLOAD_LDS16(bkey + (size_t)(r0 + row) * Hdim + kc + k8 * 8, As + u * 8);
    }
    // stage B: 128 n x 32 k bf16 (8 KiB), fully contiguous source
#pragma unroll
    for (int it = 0; it < 2; ++it) {
      int u = it * 256 + tid;
      GLOAD_LDS16(ubt + ((size_t)nt * 16384 + (kc >> 3) * 128 + u) * 8, Bs + u * 8);
    }
    __syncthreads();

    bf16x8 afr[4], bfr[4];
#pragma unroll
    for (int i = 0; i < 4; ++i)
      afr[i] = *(const bf16x8*)&As[(quad * 128 + wm + i * 16 + l16) * 8];
#pragma unroll
    for (int j = 0; j < 4; ++j)
      bfr[j] = *(const bf16x8*)&Bs[(quad * 128 + wn + j * 16 + l16) * 8];

#pragma unroll
    for (int i = 0; i < 4; ++i)
#pragma unroll
      for (int j = 0; j < 4; ++j)
        acc[i][j] = __builtin_amdgcn_mfma_f32_16x16x32_bf16(afr[i], bfr[j], acc[i][j], 0, 0, 0);

    __syncthreads();
  }

  // stage qc tile (32 b-rows x 128 n-cols) into LDS (reuse ABs as float[4096])
  float* qcs = (float*)ABs;
#pragma unroll
  for (int it = 0; it < 16; ++it) {
    int u = it * 256 + tid;
    qcs[u] = qc[(u >> 7) * Hdim + n0 + (u & 127)];
  }
  __syncthreads();

  float vav[4];
#pragma unroll
  for (int j = 0; j < 4; ++j) vav[j] = va[n0 + wn + j * 16 + l16];

  // C/D layout (m89): col = lane&15 (n), row = quad*4 + reg (m)
#pragma unroll
  for (int i = 0; i < 4; ++i) {
#pragma unroll
    for (int rg = 0; rg < 4; ++rg) {
      int b = (i & 1) * 16 + quad * 4 + rg;
      float sum = 0.f;
#pragma unroll
      for (int j = 0; j < 4; ++j) {
        float v = acc[i][j][rg] + qcs[b * 128 + wn + j * 16 + l16];
        v = fminf(fmaxf(v, -15.f), 15.f);
        float e = __expf(2.f * v);
        sum += (e - 1.f) * __builtin_amdgcn_rcpf(e + 1.f) * vav[j];
      }
#pragma unroll
      for (int off = 1; off < 16; off <<= 1)
        sum += __shfl_xor(sum, off, 64);
      if (l16 == 0)
        red[(wm + i * 16 + quad * 4 + rg) * 2 + (w >> 1)] = sum;
    }
  }
  __syncthreads();
  if (tid < 128)
    part[(size_t)(r0 + tid) * 8 + nt] = red[tid * 2] + red[tid * 2 + 1];
}

// ---------------------------------------------------------------------------
// Fallback fp32-A GEMM (known-good R1 kernel) in case ws can't hold bkey.
__global__ __launch_bounds__(256) void gemm_scores_kernel(const float* __restrict__ key,
                                                          const __bf16* __restrict__ ubt,
                                                          const float* __restrict__ qc,
                                                          const float* __restrict__ va,
                                                          float* __restrict__ part) {
  __shared__ __align__(16) float AsQ[4096];
  __shared__ __align__(16) __bf16 Bs[4096];
  __shared__ float red[256];

  const int tid  = threadIdx.x;
  const int w    = tid >> 6;
  const int lane = tid & 63;
  const int quad = lane >> 4;
  const int l16  = lane & 15;
  const int l   = blockIdx.x;
  const int xcd = l & 7;
  const int i2  = l >> 3;
  const int mt  = xcd * 64 + (i2 >> 3);
  const int nt  = i2 & 7;
  const int r0 = mt * 128;
  const int n0 = nt * 128;
  const int wm = (w & 1) * 64;
  const int wn = (w >> 1) * 64;

  f32x4 acc[4][4] = {};

  for (int kc = 0; kc < Hdim; kc += 32) {
#pragma unroll
    for (int it = 0; it < 4; ++it) {
      int u  = it * 256 + tid;
      int k4 = u >> 7, row = u & 127;
      GLOAD_LDS16(key + (size_t)(r0 + row) * Hdim + kc + k4 * 4, AsQ + u * 4);
    }
#pragma unroll
    for (int it = 0; it < 2; ++it) {
      int u = it * 256 + tid;
      GLOAD_LDS16(ubt + ((size_t)nt * 16384 + (kc >> 3) * 128 + u) * 8, Bs + u * 8);
    }
    __syncthreads();

    bf16x8 bfr[4];
#pragma unroll
    for (int j = 0; j < 4; ++j)
      bfr[j] = *(const bf16x8*)&Bs[(quad * 128 + wn + j * 16 + l16) * 8];

    bf16x8 afr[4];
#pragma unroll
    for (int i = 0; i < 4; ++i) {
      int ml = wm + i * 16 + l16;
      float4 f0 = *(const float4*)&AsQ[((quad * 2) * 128 + ml) * 4];
      float4 f1 = *(const float4*)&AsQ[((quad * 2 + 1) * 128 + ml) * 4];
      bf16x8 a;
      a[0] = (__bf16)f0.x; a[1] = (__bf16)f0.y; a[2] = (__bf16)f0.z; a[3] = (__bf16)f0.w;
      a[4] = (__bf16)f1.x; a[5] = (__bf16)f1.y; a[6] = (__bf16)f1.z; a[7] = (__bf16)f1.w;
      afr[i] = a;
    }

#pragma unroll
    for (int i = 0; i < 4; ++i)
#pragma unroll
      for (int j = 0; j < 4; ++j)
        acc[i][j] = __builtin_amdgcn_mfma_f32_16x16x32_bf16(afr[i], bfr[j], acc[i][j], 0, 0, 0);

    __syncthreads();
  }

#pragma unroll
  for (int it = 0; it < 16; ++it) {
    int u = it * 256 + tid;
    AsQ[u] = qc[(u >> 7) * Hdim + n0 + (u & 127)];
  }
  __syncthreads();

  float vav[4];
#pragma unroll
  for (int j = 0; j < 4; ++j) vav[j] = va[n0 + wn + j * 16 + l16];

#pragma unroll
  for (int i = 0; i < 4; ++i) {
#pragma unroll
    for (int rg = 0; rg < 4; ++rg) {
      int b = (i & 1) * 16 + quad * 4 + rg;
      float sum = 0.f;
#pragma unroll
      for (int j = 0; j < 4; ++j) {
        float v = acc[i][j][rg] + AsQ[b * 128 + wn + j * 16 + l16];
        v = fminf(fmaxf(v, -15.f), 15.f);
        float e = __expf(2.f * v);
        sum += (e - 1.f) * __builtin_amdgcn_rcpf(e + 1.f) * vav[j];
      }
#pragma unroll
      for (int off = 1; off < 16; off <<= 1)
        sum += __shfl_xor(sum, off, 64);
      if (l16 == 0)
        red[(wm + i * 16 + quad * 4 + rg) * 2 + (w >> 1)] = sum;
    }
  }
  __syncthreads();
  if (tid < 128)
    part[(size_t)(r0 + tid) * 8 + nt] = red[tid * 2] + red[tid * 2 + 1];
}

// ---------------------------------------------------------------------------
__global__ __launch_bounds__(256) void softmax_kernel(const float* __restrict__ part,
                                                      float* __restrict__ dout) {
  int b = blockIdx.x, t = threadIdx.x;
  int w = t >> 6, lane = t & 63;
  __shared__ float red1[4], red2[4];
  float sc[8];
  float m = -1e30f;
#pragma unroll
  for (int c = 0; c < 8; ++c) {
    int s = c * 256 + t;
    const float4* p = (const float4*)&part[(size_t)(s * 32 + b) * 8];
    float4 p0 = p[0], p1 = p[1];
    float v = ((p0.x + p0.y) + (p0.z + p0.w)) + ((p1.x + p1.y) + (p1.z + p1.w));
    sc[c] = v;
    m = fmaxf(m, v);
  }
#pragma unroll
  for (int off = 1; off < 64; off <<= 1) m = fmaxf(m, __shfl_xor(m, off, 64));
  if (lane == 0) red1[w] = m;
  __syncthreads();
  m = fmaxf(fmaxf(red1[0], red1[1]), fmaxf(red1[2], red1[3]));
  float sum = 0.f;
#pragma unroll
  for (int c = 0; c < 8; ++c) { sc[c] = __expf(sc[c] - m); sum += sc[c]; }
#pragma unroll
  for (int off = 1; off < 64; off <<= 1) sum += __shfl_xor(sum, off, 64);
  if (lane == 0) red2[w] = sum;
  __syncthreads();
  float inv = 1.f / (red2[0] + red2[1] + red2[2] + red2[3]);
#pragma unroll
  for (int c = 0; c < 8; ++c)
    dout[32768 + b * 2048 + c * 256 + t] = sc[c] * inv;
}

// ---------------------------------------------------------------------------
__global__ __launch_bounds__(256) void ctx_part_kernel(const float* __restrict__ key,
                                                       const float* __restrict__ dout,
                                                       float* __restrict__ cpart) {
  int sc = blockIdx.x;
  int b  = blockIdx.y;
  int t  = threadIdx.x;
  float4 acc = make_float4(0.f, 0.f, 0.f, 0.f);
  int s0 = sc * 64;
#pragma unroll 8
  for (int s = s0; s < s0 + 64; ++s) {
    float wgt = dout[32768 + b * 2048 + s];
    float4 k4 = *(const float4*)&key[((size_t)(s * 32 + b) << 10) + t * 4];
    acc.x = fmaf(wgt, k4.x, acc.x);
    acc.y = fmaf(wgt, k4.y, acc.y);
    acc.z = fmaf(wgt, k4.z, acc.z);
    acc.w = fmaf(wgt, k4.w, acc.w);
  }
  *(float4*)&cpart[((size_t)(sc * 32 + b) << 10) + t * 4] = acc;
}

__global__ __launch_bounds__(256) void ctx_reduce_kernel(const float* __restrict__ cpart,
                                                         float* __restrict__ dout) {
  int o = blockIdx.x * 256 + threadIdx.x;
  int b = o >> 10, h = o & 1023;
  float s = 0.f;
#pragma unroll
  for (int sc = 0; sc < 32; ++sc)
    s += cpart[((size_t)(sc * 32 + b) << 10) + h];
  dout[o] = s;
}

// ---------------------------------------------------------------------------
extern "C" void kernel_launch(void* const* d_in, const int* in_sizes, int n_in,
                              void* d_out, int out_size, void* d_ws, size_t ws_size,
                              hipStream_t stream) {
  const float* q   = (const float*)d_in[0];
  const float* key = (const float*)d_in[1];
  const float* Waw = (const float*)d_in[2];
  const float* Wab = (const float*)d_in[3];
  const float* Uaw = (const float*)d_in[4];
  const float* Uab = (const float*)d_in[5];
  const float* vaw = (const float*)d_in[6];
  float* out = (float*)d_out;  // [0,32768): context ; [32768,98304): weights

  char* ws = (char*)d_ws;
  float*  qc    = (float*)(ws);                                 // 128 KiB
  __bf16* ubt   = (__bf16*)(ws + 131072);                       // 2 MiB
  float*  part  = (float*)(ws + 131072 + 2097152);              // 2 MiB
  float*  cpart = (float*)(ws + 131072 + 2097152 + 2097152);    // 4 MiB
  __bf16* bkey  = (__bf16*)(ws + 131072 + 2097152 + 2097152 + 4194304);  // 128 MiB
  const size_t need = 131072ull + 2097152 + 2097152 + 4194304 + 134217728;

  convert_ua_kernel<<<512, 256, 0, stream>>>(Uaw, ubt);
  qc_kernel<<<dim3(4, 32), 256, 0, stream>>>(q, Waw, Wab, Uab, qc);
  if (ws_size >= need) {
    convert_key_kernel<<<32768, 256, 0, stream>>>(key, bkey);
    gemm_scores_bf16_kernel<<<4096, 256, 0, stream>>>(bkey, ubt, qc, vaw, part);
  } else {
    gemm_scores_kernel<<<4096, 256, 0, stream>>>(key, ubt, qc, vaw, part);
  }
  softmax_kernel<<<32, 256, 0, stream>>>(part, out);
  ctx_part_kernel<<<dim3(32, 32), 256, 0, stream>>>(key, out, cpart);
  ctx_reduce_kernel<<<128, 256, 0, stream>>>(cpart, out);
}